// Round 12
// baseline (225.926 us; speedup 1.0000x reference)
//
#include <hip/hip_runtime.h>

typedef unsigned short u16;
typedef __attribute__((ext_vector_type(8))) short short8;
typedef __attribute__((ext_vector_type(4))) float f32x4;

#define DEV __device__ __forceinline__

DEV u16 f2bf(float f) {
  unsigned u = __float_as_uint(f);
  u += 0x7FFF + ((u >> 16) & 1);
  return (u16)(u >> 16);
}
DEV float bf2f(u16 b) { return __uint_as_float(((unsigned)b) << 16); }

// pack bf16(a) into [15:0], bf16(b) into [31:16] by truncation (1x v_perm_b32)
DEV unsigned pk_trunc(float a, float b) {
  return __builtin_amdgcn_perm(__float_as_uint(b), __float_as_uint(a), 0x07060302u);
}

DEV void g2l16(const u16* g, u16* l) {
  __builtin_amdgcn_global_load_lds((__attribute__((address_space(1))) void*)(g),
                                   (__attribute__((address_space(3))) void*)(l), 16, 0, 0);
}

// ---------------- fp32 -> bf16 convert (x) ----------------
__global__ __launch_bounds__(256) void k_cvt(const float* __restrict__ x,
                                             u16* __restrict__ o, int n4) {
  int i = blockIdx.x * 256 + threadIdx.x;
  if (i >= n4) return;
  float4 v = ((const float4*)x)[i];
  ushort4 r;
  r.x = f2bf(v.x); r.y = f2bf(v.y); r.z = f2bf(v.z); r.w = f2bf(v.w);
  ((ushort4*)o)[i] = r;
}

// ---------------- transpose + convert: W (K,N) f32 -> Wt (N,K) bf16 ----------------
__global__ __launch_bounds__(256) void k_tc(const float* __restrict__ W,
                                            u16* __restrict__ Wt, int K, int N) {
  __shared__ float t[32][33];
  int tx = threadIdx.x & 31, ty = threadIdx.x >> 5;
  int n0 = blockIdx.x * 32, k0 = blockIdx.y * 32;
#pragma unroll
  for (int i = 0; i < 4; ++i)
    t[ty + i * 8][tx] = W[(size_t)(k0 + ty + i * 8) * N + n0 + tx];
  __syncthreads();
#pragma unroll
  for (int i = 0; i < 4; ++i)
    Wt[(size_t)(n0 + ty + i * 8) * K + k0 + tx] = f2bf(t[tx][ty + i * 8]);
}

// ---------------- GEMM: A (M,K) bf16 row-major, Bt (N,K) bf16 row-major ----------------
// EPI=0: QKV epilogue -> scatter q/k/v to head layouts, RoPE fused on q,k (d<32)
// EPI=1: plain f32 store
template <int EPI>
__global__ __launch_bounds__(256) void k_gemm(
    const u16* __restrict__ A, const u16* __restrict__ Bt,
    int M, int N, int K,
    u16* __restrict__ qw, u16* __restrict__ kw, u16* __restrict__ vw,
    float* __restrict__ of, const float* __restrict__ sn,
    const float* __restrict__ cs, float qscale) {
  __shared__ __align__(16) u16 As[128 * 64];
  __shared__ __align__(16) u16 Bs[128 * 64];
  const int t = threadIdx.x;
  const int wv = t >> 6, lane = t & 63;
  const int a15 = lane & 15, g = lane >> 4;
  const int wr = wv >> 1, wc = wv & 1;
  const int m0 = blockIdx.x * 128, n0 = blockIdx.y * 128;
  const int gr = lane >> 3, gc = (lane & 7) * 8;

  f32x4 acc[4][4];
#pragma unroll
  for (int i = 0; i < 4; ++i)
#pragma unroll
    for (int j = 0; j < 4; ++j)
#pragma unroll
      for (int r = 0; r < 4; ++r) acc[i][j][r] = 0.f;

  for (int k0 = 0; k0 < K; k0 += 64) {
#pragma unroll
    for (int c4 = 0; c4 < 4; ++c4) {
      int c = wv * 4 + c4;
      g2l16(A + (size_t)(m0 + c * 8 + gr) * K + k0 + gc, &As[c * 512]);
      g2l16(Bt + (size_t)(n0 + c * 8 + gr) * K + k0 + gc, &Bs[c * 512]);
    }
    __syncthreads();
#pragma unroll
    for (int ks = 0; ks < 2; ++ks) {
      short8 af[4], bf[4];
#pragma unroll
      for (int mi = 0; mi < 4; ++mi)
        af[mi] = *(const short8*)&As[(wr * 64 + mi * 16 + a15) * 64 + ks * 32 + g * 8];
#pragma unroll
      for (int ni = 0; ni < 4; ++ni)
        bf[ni] = *(const short8*)&Bs[(wc * 64 + ni * 16 + a15) * 64 + ks * 32 + g * 8];
#pragma unroll
      for (int mi = 0; mi < 4; ++mi)
#pragma unroll
        for (int ni = 0; ni < 4; ++ni)
          acc[mi][ni] = __builtin_amdgcn_mfma_f32_16x16x32_bf16(af[mi], bf[ni], acc[mi][ni], 0, 0, 0);
    }
    __syncthreads();
  }

  if (EPI == 0) {
    const int part = n0 >> 10;  // 0=q 1=k 2=v
    if (part <= 1) {
      const float sc = (part == 0) ? qscale : 1.f;
      u16* dst = (part == 0) ? qw : kw;
#pragma unroll
      for (int mi = 0; mi < 4; ++mi) {
#pragma unroll
        for (int ni = 0; ni < 4; ++ni) {
          int col = n0 + wc * 64 + ni * 16 + a15;
          int rem = col & 1023, h = rem >> 6, d = rem & 63;
          int row = m0 + wr * 64 + mi * 16 + g * 4;
          int b = row >> 11, n = row & 2047;
          size_t bh = (size_t)b * 16 + h;
#pragma unroll
          for (int r = 0; r < 4; ++r) {
            float v = acc[mi][ni][r];
            float p = __shfl_xor(v, 1);  // RoPE partner (d^1), uniform ctrl flow
            float outv = v;
            if (d < 32) {
              int nr = n + r;
              float c = cs[nr * 32 + d], s = sn[nr * 32 + d];
              outv = v * c + ((d & 1) ? p * s : -p * s);
            }
            dst[(bh * 2048 + n + r) * 64 + d] = f2bf(outv * sc);
          }
        }
      }
    } else {
#pragma unroll
      for (int mi = 0; mi < 4; ++mi) {
#pragma unroll
        for (int ni = 0; ni < 4; ++ni) {
          int col = n0 + wc * 64 + ni * 16 + a15;
          int rem = col & 1023, h = rem >> 6, d = rem & 63;
          int row = m0 + wr * 64 + mi * 16 + g * 4;
          int b = row >> 11, n = row & 2047;
          size_t bh = (size_t)b * 16 + h;
          ushort4 pk;
          pk.x = f2bf(acc[mi][ni][0]); pk.y = f2bf(acc[mi][ni][1]);
          pk.z = f2bf(acc[mi][ni][2]); pk.w = f2bf(acc[mi][ni][3]);
          *(ushort4*)&vw[(bh * 64 + d) * 2048 + n] = pk;  // v^T: (bh, d, n)
        }
      }
    }
  } else {
#pragma unroll
    for (int mi = 0; mi < 4; ++mi)
#pragma unroll
      for (int ni = 0; ni < 4; ++ni) {
        int col = n0 + wc * 64 + ni * 16 + a15;
        int row = m0 + wr * 64 + mi * 16 + g * 4;
#pragma unroll
        for (int r = 0; r < 4; ++r)
          of[(size_t)(row + r) * N + col] = acc[mi][ni][r];
      }
  }
}

// ---------------- fused flash attention (hybrid: dbuf prefetch + high TLP) ----------
// grid 2048 (64 heads x 32 q-blocks of 64 rows), XCD swizzle:
// head = (id&7)|((id>>8)<<3) -> XCD c owns heads==c (mod 8) (KV set = its L2).
// 4 waves x 16 q-rows (1 fragment/wave, VGPR ~60). K and V double-buffered in LDS
// (prefetch j+1 right after the single per-iter barrier; staging drains at the NEXT
// barrier after a full compute phase). LDS 40KB -> 4 blocks/CU = 16 waves/CU.
__global__ __launch_bounds__(256, 3) void k_attn(
    const u16* __restrict__ q, const u16* __restrict__ kk, const u16* __restrict__ vT,
    u16* __restrict__ o) {
  __shared__ __align__(16) u16 Ks[2][4096];
  __shared__ __align__(16) u16 Vs[2][4096];
  __shared__ __align__(16) u16 Pl[4][1024];  // per-wave 2KB, XOR-swizzled
  const int t = threadIdx.x;
  const int w = t >> 6, lane = t & 63;
  const int a15 = lane & 15, g = lane >> 4;
  const int id = blockIdx.x;
  const int bh = (id & 7) | ((id >> 8) << 3);   // XCD-local head
  const int qb = (id >> 3) & 31;
  const int q0 = qb * 64 + w * 16;
  const size_t hb = (size_t)bh * (2048 * 64);

  short8 qf[2];
#pragma unroll
  for (int h = 0; h < 2; ++h)
    qf[h] = *(const short8*)&q[hb + (size_t)(q0 + a15) * 64 + h * 32 + g * 8];

  int ksrc[2], vsrc[2];
#pragma unroll
  for (int c = 0; c < 2; ++c) {
    int L = w * 2048 + c * 1024 + lane * 16;  // LDS byte (linear dest)
    int row = L >> 7;
    int sb = L ^ ((row & 7) << 4);            // inverse-swizzled source byte
    ksrc[c] = sb >> 1;
    vsrc[c] = row * 2048 + ((sb & 127) >> 1);
  }
  const u16* kg = kk + hb;
  const u16* vg = vT + (size_t)bh * (64 * 2048);

#define STAGE(b, j0) do {                                        \
    g2l16(kg + (size_t)(j0) * 64 + ksrc[0], &Ks[b][w * 1024]);   \
    g2l16(kg + (size_t)(j0) * 64 + ksrc[1], &Ks[b][w * 1024 + 512]); \
    g2l16(vg + (j0) + vsrc[0], &Vs[b][w * 1024]);                \
    g2l16(vg + (j0) + vsrc[1], &Vs[b][w * 1024 + 512]);          \
  } while (0)

  const f32x4 z4 = {0.f, 0.f, 0.f, 0.f};
  const short8 ones = {(short)0x3F80, (short)0x3F80, (short)0x3F80, (short)0x3F80,
                       (short)0x3F80, (short)0x3F80, (short)0x3F80, (short)0x3F80};
  f32x4 accO[4], ssum = z4;
#pragma unroll
  for (int dc = 0; dc < 4; ++dc) accO[dc] = z4;

  STAGE(0, 0);
  int cur = 0;
  for (int jt = 0; jt < 32; ++jt) {
    __syncthreads();                         // stage(cur) landed (vmcnt drained here)
    if (jt < 31) STAGE(cur ^ 1, (jt + 1) * 64);  // prefetch next, hidden by compute

    // ---- QK^T: S^T = mfma(K, Q) ----
    f32x4 st[4];
    const char* Kb = (const char*)Ks[cur];
    __builtin_amdgcn_s_setprio(1);
#pragma unroll
    for (int jc = 0; jc < 4; ++jc) {
      int row = jc * 16 + a15;
      int sw = (row & 7) << 4;
      short8 ka0 = *(const short8*)(Kb + ((row * 128 + g * 16) ^ sw));
      short8 ka1 = *(const short8*)(Kb + ((row * 128 + 64 + g * 16) ^ sw));
      st[jc] = __builtin_amdgcn_mfma_f32_16x16x32_bf16(ka0, qf[0], z4, 0, 0, 0);
      st[jc] = __builtin_amdgcn_mfma_f32_16x16x32_bf16(ka1, qf[1], st[jc], 0, 0, 0);
    }
    __builtin_amdgcn_s_setprio(0);
    // ---- V fragments from LDS (latency hidden under softmax VALU) ----
    short8 vf[2][4];
    const char* Vb = (const char*)Vs[cur];
#pragma unroll
    for (int kt = 0; kt < 2; ++kt)
#pragma unroll
      for (int dc = 0; dc < 4; ++dc) {
        int row = dc * 16 + a15;
        vf[kt][dc] = *(const short8*)(Vb + ((row * 128 + kt * 64 + g * 16) ^ ((row & 7) << 4)));
      }
    // ---- softmax: P = exp2(S) (builtin), pack via v_perm truncation ----
#pragma unroll
    for (int jc = 0; jc < 4; ++jc) {
      float e0 = __builtin_amdgcn_exp2f(st[jc][0]);
      float e1 = __builtin_amdgcn_exp2f(st[jc][1]);
      float e2 = __builtin_amdgcn_exp2f(st[jc][2]);
      float e3 = __builtin_amdgcn_exp2f(st[jc][3]);
      uint2 pw;
      pw.x = pk_trunc(e0, e1);
      pw.y = pk_trunc(e2, e3);
      int byte = (a15 * 128 + (jc * 16 + g * 4) * 2) ^ ((a15 & 7) << 4);
      *(uint2*)((char*)Pl[w] + byte) = pw;
    }
    // ---- PV: O += P V ; row sums via ones-MFMA ----
    __builtin_amdgcn_s_setprio(1);
#pragma unroll
    for (int kt = 0; kt < 2; ++kt) {
      int byteA = (a15 * 128 + kt * 64 + g * 16) ^ ((a15 & 7) << 4);
      short8 pa = *(const short8*)((const char*)Pl[w] + byteA);
      ssum = __builtin_amdgcn_mfma_f32_16x16x32_bf16(pa, ones, ssum, 0, 0, 0);
#pragma unroll
      for (int dc = 0; dc < 4; ++dc)
        accO[dc] = __builtin_amdgcn_mfma_f32_16x16x32_bf16(pa, vf[kt][dc], accO[dc], 0, 0, 0);
    }
    __builtin_amdgcn_s_setprio(0);
    cur ^= 1;
  }
#undef STAGE

  const int b = bh >> 4, h = bh & 15;
  float rs[4];
#pragma unroll
  for (int r = 0; r < 4; ++r) rs[r] = 1.f / ssum[r];  // lane holds rows g*4+r sums
#pragma unroll
  for (int dc = 0; dc < 4; ++dc)
#pragma unroll
    for (int r = 0; r < 4; ++r) {
      int n = q0 + g * 4 + r;
      o[((size_t)b * 2048 + n) * 1024 + h * 64 + dc * 16 + a15] = f2bf(accO[dc][r] * rs[r]);
    }
}

extern "C" void kernel_launch(void* const* d_in, const int* in_sizes, int n_in,
                              void* d_out, int out_size, void* d_ws, size_t ws_size,
                              hipStream_t stream) {
  const float* x = (const float*)d_in[0];
  const float* sn = (const float*)d_in[1];
  const float* cs = (const float*)d_in[2];
  const float* Wqkv = (const float*)d_in[3];
  const float* Wout = (const float*)d_in[4];
  float* out = (float*)d_out;

  u16* ws = (u16*)d_ws;
  u16* xb = ws;                              // 8192*1024
  u16* wqkvT = xb + 8192ull * 1024;          // 3072*1024
  u16* woutT = wqkvT + 3072ull * 1024;       // 1024*1024
  u16* qw = woutT + 1024ull * 1024;          // 64*2048*64
  u16* kw = qw + 64ull * 2048 * 64;
  u16* vw = kw + 64ull * 2048 * 64;
  u16* attn = xb;  // alias: x consumed by QKV GEMM before attention writes

  const float qscale = 0.125f * 1.4426950408889634f;  // DH^-0.5 * log2(e)

  k_cvt<<<8192, 256, 0, stream>>>(x, xb, 8192 * 1024 / 4);
  k_tc<<<dim3(96, 32), 256, 0, stream>>>(Wqkv, wqkvT, 1024, 3072);
  k_tc<<<dim3(32, 32), 256, 0, stream>>>(Wout, woutT, 1024, 1024);
  k_gemm<0><<<dim3(64, 24), 256, 0, stream>>>(xb, wqkvT, 8192, 3072, 1024,
                                              qw, kw, vw, nullptr, sn, cs, qscale);
  k_attn<<<2048, 256, 0, stream>>>(qw, kw, vw, attn);
  k_gemm<1><<<dim3(64, 8), 256, 0, stream>>>(attn, woutT, 8192, 1024, 1024,
                                             nullptr, nullptr, nullptr, out, nullptr, nullptr, 1.f);
}

// Round 13
// 216.253 us; speedup vs baseline: 1.0447x; 1.0447x over previous
//
#include <hip/hip_runtime.h>

typedef unsigned short u16;
typedef __attribute__((ext_vector_type(8))) short short8;
typedef __attribute__((ext_vector_type(4))) float f32x4;

#define DEV __device__ __forceinline__

DEV u16 f2bf(float f) {
  unsigned u = __float_as_uint(f);
  u += 0x7FFF + ((u >> 16) & 1);
  return (u16)(u >> 16);
}
DEV float bf2f(u16 b) { return __uint_as_float(((unsigned)b) << 16); }

// pack bf16(a) into [15:0], bf16(b) into [31:16] by truncation (1x v_perm_b32)
DEV unsigned pk_trunc(float a, float b) {
  return __builtin_amdgcn_perm(__float_as_uint(b), __float_as_uint(a), 0x07060302u);
}

DEV void g2l16(const u16* g, u16* l) {
  __builtin_amdgcn_global_load_lds((__attribute__((address_space(1))) void*)(g),
                                   (__attribute__((address_space(3))) void*)(l), 16, 0, 0);
}

// ---------------- fused prep: x cvt (blocks 0..8191), Wqkv tc (8192..11263),
// ---------------- Wout tc (11264..12287) — one launch instead of three
__global__ __launch_bounds__(256) void k_prep(const float* __restrict__ x,
                                              u16* __restrict__ xb,
                                              const float* __restrict__ Wqkv,
                                              u16* __restrict__ wqkvT,
                                              const float* __restrict__ Wout,
                                              u16* __restrict__ woutT) {
  __shared__ float t[32][33];
  const int blk = blockIdx.x;
  if (blk < 8192) {
    int i = blk * 256 + threadIdx.x;
    float4 v = ((const float4*)x)[i];
    ushort4 r;
    r.x = f2bf(v.x); r.y = f2bf(v.y); r.z = f2bf(v.z); r.w = f2bf(v.w);
    ((ushort4*)xb)[i] = r;
    return;
  }
  const float* W;
  u16* Wt;
  int K = 1024, N, local;
  if (blk < 11264) {
    W = Wqkv; Wt = wqkvT; N = 3072; local = blk - 8192;
  } else {
    W = Wout; Wt = woutT; N = 1024; local = blk - 11264;
  }
  int nb = N / 32;
  int n0 = (local % nb) * 32, k0 = (local / nb) * 32;
  int tx = threadIdx.x & 31, ty = threadIdx.x >> 5;
#pragma unroll
  for (int i = 0; i < 4; ++i)
    t[ty + i * 8][tx] = W[(size_t)(k0 + ty + i * 8) * N + n0 + tx];
  __syncthreads();
#pragma unroll
  for (int i = 0; i < 4; ++i)
    Wt[(size_t)(n0 + ty + i * 8) * K + k0 + tx] = f2bf(t[tx][ty + i * 8]);
}

// ---------------- GEMM: A (M,K) bf16 row-major, Bt (N,K) bf16 row-major ----------------
// EPI=0: 1D grid 1536, XCD by-chunk swizzle (B-panels L2-resident per XCD);
//        epilogue scatters q/k/v to head layouts, RoPE fused on q,k (d<32)
// EPI=1: 2D grid, plain f32 store
template <int EPI>
__global__ __launch_bounds__(256) void k_gemm(
    const u16* __restrict__ A, const u16* __restrict__ Bt,
    int M, int N, int K,
    u16* __restrict__ qw, u16* __restrict__ kw, u16* __restrict__ vw,
    float* __restrict__ of, const float* __restrict__ sn,
    const float* __restrict__ cs, float qscale) {
  __shared__ __align__(16) u16 As[128 * 64];
  __shared__ __align__(16) u16 Bs[128 * 64];
  const int t = threadIdx.x;
  const int wv = t >> 6, lane = t & 63;
  const int a15 = lane & 15, g = lane >> 4;
  const int wr = wv >> 1, wc = wv & 1;
  int m0, n0;
  if (EPI == 0) {
    // 1536 blocks: XCD c = id&7 owns by in [c*3, c*3+3) -> B working set 768KB = L2-hit
    int id = blockIdx.x;
    int c = id & 7, j = id >> 3;
    m0 = (j & 63) * 128;
    n0 = (c * 3 + (j >> 6)) * 128;
  } else {
    m0 = blockIdx.x * 128;
    n0 = blockIdx.y * 128;
  }
  const int gr = lane >> 3, gc = (lane & 7) * 8;

  f32x4 acc[4][4];
#pragma unroll
  for (int i = 0; i < 4; ++i)
#pragma unroll
    for (int j = 0; j < 4; ++j)
#pragma unroll
      for (int r = 0; r < 4; ++r) acc[i][j][r] = 0.f;

  for (int k0 = 0; k0 < K; k0 += 64) {
#pragma unroll
    for (int c4 = 0; c4 < 4; ++c4) {
      int c = wv * 4 + c4;
      g2l16(A + (size_t)(m0 + c * 8 + gr) * K + k0 + gc, &As[c * 512]);
      g2l16(Bt + (size_t)(n0 + c * 8 + gr) * K + k0 + gc, &Bs[c * 512]);
    }
    __syncthreads();
#pragma unroll
    for (int ks = 0; ks < 2; ++ks) {
      short8 af[4], bf[4];
#pragma unroll
      for (int mi = 0; mi < 4; ++mi)
        af[mi] = *(const short8*)&As[(wr * 64 + mi * 16 + a15) * 64 + ks * 32 + g * 8];
#pragma unroll
      for (int ni = 0; ni < 4; ++ni)
        bf[ni] = *(const short8*)&Bs[(wc * 64 + ni * 16 + a15) * 64 + ks * 32 + g * 8];
#pragma unroll
      for (int mi = 0; mi < 4; ++mi)
#pragma unroll
        for (int ni = 0; ni < 4; ++ni)
          acc[mi][ni] = __builtin_amdgcn_mfma_f32_16x16x32_bf16(af[mi], bf[ni], acc[mi][ni], 0, 0, 0);
    }
    __syncthreads();
  }

  if (EPI == 0) {
    const int part = n0 >> 10;  // 0=q 1=k 2=v
    if (part <= 1) {
      const float sc = (part == 0) ? qscale : 1.f;
      u16* dst = (part == 0) ? qw : kw;
#pragma unroll
      for (int mi = 0; mi < 4; ++mi) {
#pragma unroll
        for (int ni = 0; ni < 4; ++ni) {
          int col = n0 + wc * 64 + ni * 16 + a15;
          int rem = col & 1023, h = rem >> 6, d = rem & 63;
          int row = m0 + wr * 64 + mi * 16 + g * 4;
          int b = row >> 11, n = row & 2047;
          size_t bh = (size_t)b * 16 + h;
#pragma unroll
          for (int r = 0; r < 4; ++r) {
            float v = acc[mi][ni][r];
            float p = __shfl_xor(v, 1);  // RoPE partner (d^1), uniform ctrl flow
            float outv = v;
            if (d < 32) {
              int nr = n + r;
              float c = cs[nr * 32 + d], s = sn[nr * 32 + d];
              outv = v * c + ((d & 1) ? p * s : -p * s);
            }
            dst[(bh * 2048 + n + r) * 64 + d] = f2bf(outv * sc);
          }
        }
      }
    } else {
#pragma unroll
      for (int mi = 0; mi < 4; ++mi) {
#pragma unroll
        for (int ni = 0; ni < 4; ++ni) {
          int col = n0 + wc * 64 + ni * 16 + a15;
          int rem = col & 1023, h = rem >> 6, d = rem & 63;
          int row = m0 + wr * 64 + mi * 16 + g * 4;
          int b = row >> 11, n = row & 2047;
          size_t bh = (size_t)b * 16 + h;
          ushort4 pk;
          pk.x = f2bf(acc[mi][ni][0]); pk.y = f2bf(acc[mi][ni][1]);
          pk.z = f2bf(acc[mi][ni][2]); pk.w = f2bf(acc[mi][ni][3]);
          *(ushort4*)&vw[(bh * 64 + d) * 2048 + n] = pk;  // v^T: (bh, d, n)
        }
      }
    }
  } else {
#pragma unroll
    for (int mi = 0; mi < 4; ++mi)
#pragma unroll
      for (int ni = 0; ni < 4; ++ni) {
        int col = n0 + wc * 64 + ni * 16 + a15;
        int row = m0 + wr * 64 + mi * 16 + g * 4;
#pragma unroll
        for (int r = 0; r < 4; ++r)
          of[(size_t)(row + r) * N + col] = acc[mi][ni][r];
      }
  }
}

// ---------------- fused flash attention (round-9 frozen best: 100.5us) ----------------
// 1D grid 1024, XCD swizzle: head = (id&7)|((id>>7)<<3) -> XCD c owns heads==c (mod 8),
// KV working set 4MB = its L2. K,V staged to LDS double-buffered (XOR-swizzled).
// 256 thr = 4 waves, 32 q-rows/wave (2 fragments). LDS 40KB.
__global__ __launch_bounds__(256, 3) void k_attn(
    const u16* __restrict__ q, const u16* __restrict__ kk, const u16* __restrict__ vT,
    u16* __restrict__ o) {
  __shared__ __align__(16) u16 Ks[2][4096];
  __shared__ __align__(16) u16 Vs[2][4096];
  __shared__ __align__(16) u16 Pl[4][1024];  // per-wave 2KB, XOR-swizzled
  const int t = threadIdx.x;
  const int w = t >> 6, lane = t & 63;
  const int a15 = lane & 15, g = lane >> 4;
  const int id = blockIdx.x;
  const int bh = (id & 7) | ((id >> 7) << 3);   // XCD-local head
  const int qb = (id >> 3) & 15;
  const int q0 = qb * 128 + w * 32;
  const size_t hb = (size_t)bh * (2048 * 64);

  short8 qf[2][2];
#pragma unroll
  for (int f = 0; f < 2; ++f)
#pragma unroll
    for (int h = 0; h < 2; ++h)
      qf[f][h] = *(const short8*)&q[hb + (size_t)(q0 + f * 16 + a15) * 64 + h * 32 + g * 8];

  int ksrc[2], vsrc[2];
#pragma unroll
  for (int c = 0; c < 2; ++c) {
    int L = w * 2048 + c * 1024 + lane * 16;  // LDS byte (linear dest)
    int row = L >> 7;
    int sb = L ^ ((row & 7) << 4);            // inverse-swizzled source byte
    ksrc[c] = sb >> 1;
    vsrc[c] = row * 2048 + ((sb & 127) >> 1);
  }
  const u16* kg = kk + hb;
  const u16* vg = vT + (size_t)bh * (64 * 2048);

#define STAGE(b, j0) do {                                        \
    g2l16(kg + (size_t)(j0) * 64 + ksrc[0], &Ks[b][w * 1024]);   \
    g2l16(kg + (size_t)(j0) * 64 + ksrc[1], &Ks[b][w * 1024 + 512]); \
    g2l16(vg + (j0) + vsrc[0], &Vs[b][w * 1024]);                \
    g2l16(vg + (j0) + vsrc[1], &Vs[b][w * 1024 + 512]);          \
  } while (0)

  const f32x4 z4 = {0.f, 0.f, 0.f, 0.f};
  const short8 ones = {(short)0x3F80, (short)0x3F80, (short)0x3F80, (short)0x3F80,
                       (short)0x3F80, (short)0x3F80, (short)0x3F80, (short)0x3F80};
  f32x4 accO[2][4], ssum[2];
#pragma unroll
  for (int f = 0; f < 2; ++f) {
    ssum[f] = z4;
#pragma unroll
    for (int dc = 0; dc < 4; ++dc) accO[f][dc] = z4;
  }

  STAGE(0, 0);
  int cur = 0;
  for (int jt = 0; jt < 32; ++jt) {
    __syncthreads();
    if (jt < 31) STAGE(cur ^ 1, (jt + 1) * 64);  // prefetch next, hidden by compute

    // ---- QK^T: S^T = mfma(K, Q) ----
    f32x4 st[2][4];
    const char* Kb = (const char*)Ks[cur];
    __builtin_amdgcn_s_setprio(1);
#pragma unroll
    for (int jc = 0; jc < 4; ++jc) {
      int row = jc * 16 + a15;
      int sw = (row & 7) << 4;
      short8 ka0 = *(const short8*)(Kb + ((row * 128 + g * 16) ^ sw));
      short8 ka1 = *(const short8*)(Kb + ((row * 128 + 64 + g * 16) ^ sw));
      st[0][jc] = __builtin_amdgcn_mfma_f32_16x16x32_bf16(ka0, qf[0][0], z4, 0, 0, 0);
      st[0][jc] = __builtin_amdgcn_mfma_f32_16x16x32_bf16(ka1, qf[0][1], st[0][jc], 0, 0, 0);
      st[1][jc] = __builtin_amdgcn_mfma_f32_16x16x32_bf16(ka0, qf[1][0], z4, 0, 0, 0);
      st[1][jc] = __builtin_amdgcn_mfma_f32_16x16x32_bf16(ka1, qf[1][1], st[1][jc], 0, 0, 0);
    }
    __builtin_amdgcn_s_setprio(0);
    // ---- V fragments (latency hidden under softmax VALU) ----
    short8 vf[2][4];
    const char* Vb = (const char*)Vs[cur];
#pragma unroll
    for (int kt = 0; kt < 2; ++kt)
#pragma unroll
      for (int dc = 0; dc < 4; ++dc) {
        int row = dc * 16 + a15;
        vf[kt][dc] = *(const short8*)(Vb + ((row * 128 + kt * 64 + g * 16) ^ ((row & 7) << 4)));
      }
    // ---- per fragment: softmax -> P write -> PV (single 2KB P buffer/wave) ----
#pragma unroll
    for (int f = 0; f < 2; ++f) {
#pragma unroll
      for (int jc = 0; jc < 4; ++jc) {
        float e0 = __builtin_amdgcn_exp2f(st[f][jc][0]);
        float e1 = __builtin_amdgcn_exp2f(st[f][jc][1]);
        float e2 = __builtin_amdgcn_exp2f(st[f][jc][2]);
        float e3 = __builtin_amdgcn_exp2f(st[f][jc][3]);
        uint2 pw;
        pw.x = pk_trunc(e0, e1);
        pw.y = pk_trunc(e2, e3);
        int byte = (a15 * 128 + (jc * 16 + g * 4) * 2) ^ ((a15 & 7) << 4);
        *(uint2*)((char*)Pl[w] + byte) = pw;
      }
      __builtin_amdgcn_s_setprio(1);
#pragma unroll
      for (int kt = 0; kt < 2; ++kt) {
        int byteA = (a15 * 128 + kt * 64 + g * 16) ^ ((a15 & 7) << 4);
        short8 pa = *(const short8*)((const char*)Pl[w] + byteA);
        ssum[f] = __builtin_amdgcn_mfma_f32_16x16x32_bf16(pa, ones, ssum[f], 0, 0, 0);
#pragma unroll
        for (int dc = 0; dc < 4; ++dc)
          accO[f][dc] = __builtin_amdgcn_mfma_f32_16x16x32_bf16(pa, vf[kt][dc], accO[f][dc], 0, 0, 0);
      }
      __builtin_amdgcn_s_setprio(0);
    }
    cur ^= 1;
  }
#undef STAGE

  const int b = bh >> 4, h = bh & 15;
#pragma unroll
  for (int f = 0; f < 2; ++f) {
    float rs[4];
#pragma unroll
    for (int r = 0; r < 4; ++r) rs[r] = 1.f / ssum[f][r];  // lane holds rows g*4+r sums
#pragma unroll
    for (int dc = 0; dc < 4; ++dc)
#pragma unroll
      for (int r = 0; r < 4; ++r) {
        int n = q0 + f * 16 + g * 4 + r;
        o[((size_t)b * 2048 + n) * 1024 + h * 64 + dc * 16 + a15] = f2bf(accO[f][dc][r] * rs[r]);
      }
  }
}

extern "C" void kernel_launch(void* const* d_in, const int* in_sizes, int n_in,
                              void* d_out, int out_size, void* d_ws, size_t ws_size,
                              hipStream_t stream) {
  const float* x = (const float*)d_in[0];
  const float* sn = (const float*)d_in[1];
  const float* cs = (const float*)d_in[2];
  const float* Wqkv = (const float*)d_in[3];
  const float* Wout = (const float*)d_in[4];
  float* out = (float*)d_out;

  u16* ws = (u16*)d_ws;
  u16* xb = ws;                              // 8192*1024
  u16* wqkvT = xb + 8192ull * 1024;          // 3072*1024
  u16* woutT = wqkvT + 3072ull * 1024;       // 1024*1024
  u16* qw = woutT + 1024ull * 1024;          // 64*2048*64
  u16* kw = qw + 64ull * 2048 * 64;
  u16* vw = kw + 64ull * 2048 * 64;
  u16* attn = xb;  // alias: x consumed by QKV GEMM before attention writes

  const float qscale = 0.125f * 1.4426950408889634f;  // DH^-0.5 * log2(e)

  k_prep<<<12288, 256, 0, stream>>>(x, xb, Wqkv, wqkvT, Wout, woutT);
  k_gemm<0><<<1536, 256, 0, stream>>>(xb, wqkvT, 8192, 3072, 1024,
                                      qw, kw, vw, nullptr, sn, cs, qscale);
  k_attn<<<1024, 256, 0, stream>>>(qw, kw, vw, attn);
  k_gemm<1><<<dim3(64, 8), 256, 0, stream>>>(attn, woutT, 8192, 1024, 1024,
                                             nullptr, nullptr, nullptr, out, nullptr, nullptr, 1.f);
}

// Round 14
// 213.455 us; speedup vs baseline: 1.0584x; 1.0131x over previous
//
#include <hip/hip_runtime.h>

typedef unsigned short u16;
typedef __attribute__((ext_vector_type(8))) short short8;
typedef __attribute__((ext_vector_type(4))) float f32x4;

#define DEV __device__ __forceinline__

DEV u16 f2bf(float f) {
  unsigned u = __float_as_uint(f);
  u += 0x7FFF + ((u >> 16) & 1);
  return (u16)(u >> 16);
}
DEV float bf2f(u16 b) { return __uint_as_float(((unsigned)b) << 16); }

DEV unsigned pk_trunc(float a, float b) {
  return __builtin_amdgcn_perm(__float_as_uint(b), __float_as_uint(a), 0x07060302u);
}

DEV void g2l16(const u16* g, u16* l) {
  __builtin_amdgcn_global_load_lds((__attribute__((address_space(1))) void*)(g),
                                   (__attribute__((address_space(3))) void*)(l), 16, 0, 0);
}

// ---------------- fused prep: x cvt (0..8191), Wqkv tc (8192..11263), Wout tc (rest)
__global__ __launch_bounds__(256) void k_prep(const float* __restrict__ x,
                                              u16* __restrict__ xb,
                                              const float* __restrict__ Wqkv,
                                              u16* __restrict__ wqkvT,
                                              const float* __restrict__ Wout,
                                              u16* __restrict__ woutT) {
  __shared__ float t[32][33];
  const int blk = blockIdx.x;
  if (blk < 8192) {
    int i = blk * 256 + threadIdx.x;
    float4 v = ((const float4*)x)[i];
    ushort4 r;
    r.x = f2bf(v.x); r.y = f2bf(v.y); r.z = f2bf(v.z); r.w = f2bf(v.w);
    ((ushort4*)xb)[i] = r;
    return;
  }
  const float* W;
  u16* Wt;
  int K = 1024, N, local;
  if (blk < 11264) {
    W = Wqkv; Wt = wqkvT; N = 3072; local = blk - 8192;
  } else {
    W = Wout; Wt = woutT; N = 1024; local = blk - 11264;
  }
  int nb = N / 32;
  int n0 = (local % nb) * 32, k0 = (local / nb) * 32;
  int tx = threadIdx.x & 31, ty = threadIdx.x >> 5;
#pragma unroll
  for (int i = 0; i < 4; ++i)
    t[ty + i * 8][tx] = W[(size_t)(k0 + ty + i * 8) * N + n0 + tx];
  __syncthreads();
#pragma unroll
  for (int i = 0; i < 4; ++i)
    Wt[(size_t)(n0 + ty + i * 8) * K + k0 + tx] = f2bf(t[tx][ty + i * 8]);
}

// ---------------- QKV GEMM: 8-phase 256x256 pipeline (M=8192,N=3072,K=1024) ----------
// 512 thr = 8 waves (2Mx4N), per-wave C 128x64, BK=64, LDS 128KB (2 slots).
// Per pass (1 K-tile, 4 phases): {frag ds_reads; bar; setprio+16 MFMA; bar}.
// Tile t+2 staged into the in-use slot region-granularly after reads retire:
//   ph1-start: A rows 0-63 | ph2-start: B half0 | ph3-start: A rows 64-127 |
//   ph3-end: B half1; then counted s_waitcnt vmcnt(8) + barrier (never 0 till drain).
// XOR-swizzle ^(row&7)<<4 on stage-source and frag reads (T2).
__global__ __launch_bounds__(512, 2) void k_gemm0(
    const u16* __restrict__ A, const u16* __restrict__ Bt,
    u16* __restrict__ qw, u16* __restrict__ kw, u16* __restrict__ vw,
    const float* __restrict__ sn, const float* __restrict__ cs, float qscale) {
  __shared__ __align__(16) u16 As[2][2][8192];
  __shared__ __align__(16) u16 Bs[2][2][8192];
  const int tid = threadIdx.x;
  const int wid = tid >> 6, lane = tid & 63;
  const int a15 = lane & 15, g = lane >> 4;
  const int wr = wid >> 2, wc = wid & 3;
  const int m0 = (blockIdx.x & 31) * 256, n0 = (blockIdx.x >> 5) * 256;
  const int K = 1024;
  const int srow = wid * 8 + (lane >> 3);                 // row within 64-row chunk
  const int scol = ((lane & 7) ^ (lane >> 3)) << 3;       // swizzled col (elems)
  const int swz = (a15 & 7) << 4;

#define SA(s, h, l, u) g2l16(A + (size_t)(m0 + (h)*128 + (l)*64 + srow) * K + (u)*64 + scol, \
                             &As[s][h][(l)*4096 + wid * 512])
#define SB(s, h, l, u) g2l16(Bt + (size_t)(n0 + (h)*128 + (l)*64 + srow) * K + (u)*64 + scol, \
                             &Bs[s][h][(l)*4096 + wid * 512])

  f32x4 acc[8][4];
#pragma unroll
  for (int i = 0; i < 8; ++i)
#pragma unroll
    for (int j = 0; j < 4; ++j)
#pragma unroll
      for (int r = 0; r < 4; ++r) acc[i][j][r] = 0.f;

  // prologue: stage tiles 0,1; wait own first 8; barrier
  SA(0,0,0,0); SA(0,1,0,0); SA(0,0,1,0); SA(0,1,1,0);
  SB(0,0,0,0); SB(0,0,1,0); SB(0,1,0,0); SB(0,1,1,0);
  SA(1,0,0,1); SA(1,1,0,1); SA(1,0,1,1); SA(1,1,1,1);
  SB(1,0,0,1); SB(1,0,1,1); SB(1,1,0,1); SB(1,1,1,1);
  asm volatile("s_waitcnt vmcnt(8)" ::: "memory");
  __builtin_amdgcn_s_barrier();

  short8 af[4][2], bf[4][2];
  const int brb = (wc & 1) * 64;

  for (int t = 0; t < 16; ++t) {
    const int s = t & 1, u = t + 2;
    const bool st = (u < 16);
    const char* Ab = (const char*)&As[s][wr][0];
    const char* Bb = (const char*)&Bs[s][wc >> 1][0];
    // ---- ph0: af(mi0-3) + bf(ni0-1); MFMA q0 ----
#pragma unroll
    for (int mi = 0; mi < 4; ++mi)
#pragma unroll
      for (int ks = 0; ks < 2; ++ks)
        af[mi][ks] = *(const short8*)(Ab + (((mi * 16 + a15) * 128 + ks * 64 + g * 16) ^ swz));
#pragma unroll
    for (int ni = 0; ni < 2; ++ni)
#pragma unroll
      for (int ks = 0; ks < 2; ++ks)
        bf[ni][ks] = *(const short8*)(Bb + (((brb + ni * 16 + a15) * 128 + ks * 64 + g * 16) ^ swz));
    __builtin_amdgcn_s_barrier();
    __builtin_amdgcn_s_setprio(1);
#pragma unroll
    for (int mi = 0; mi < 4; ++mi)
#pragma unroll
      for (int ni = 0; ni < 2; ++ni)
#pragma unroll
        for (int ks = 0; ks < 2; ++ks)
          acc[mi][ni] = __builtin_amdgcn_mfma_f32_16x16x32_bf16(af[mi][ks], bf[ni][ks], acc[mi][ni], 0, 0, 0);
    __builtin_amdgcn_s_setprio(0);
    __builtin_amdgcn_s_barrier();
    // ---- ph1: stage A rows0-63(u); bf(ni2-3); MFMA q1 ----
    if (st) { SA(s, 0, 0, u); SA(s, 1, 0, u); }
#pragma unroll
    for (int ni = 0; ni < 2; ++ni)
#pragma unroll
      for (int ks = 0; ks < 2; ++ks)
        bf[2 + ni][ks] = *(const short8*)(Bb + (((brb + (2 + ni) * 16 + a15) * 128 + ks * 64 + g * 16) ^ swz));
    __builtin_amdgcn_s_barrier();
    __builtin_amdgcn_s_setprio(1);
#pragma unroll
    for (int mi = 0; mi < 4; ++mi)
#pragma unroll
      for (int ni = 0; ni < 2; ++ni)
#pragma unroll
        for (int ks = 0; ks < 2; ++ks)
          acc[mi][2 + ni] = __builtin_amdgcn_mfma_f32_16x16x32_bf16(af[mi][ks], bf[2 + ni][ks], acc[mi][2 + ni], 0, 0, 0);
    __builtin_amdgcn_s_setprio(0);
    __builtin_amdgcn_s_barrier();
    // ---- ph2: stage B half0(u); af(mi4-7); MFMA q2 ----
    if (st) { SB(s, 0, 0, u); SB(s, 0, 1, u); }
#pragma unroll
    for (int mi = 0; mi < 4; ++mi)
#pragma unroll
      for (int ks = 0; ks < 2; ++ks)
        af[mi][ks] = *(const short8*)(Ab + ((((64 + mi * 16) + a15) * 128 + ks * 64 + g * 16) ^ swz));
    __builtin_amdgcn_s_barrier();
    __builtin_amdgcn_s_setprio(1);
#pragma unroll
    for (int mi = 0; mi < 4; ++mi)
#pragma unroll
      for (int ni = 0; ni < 2; ++ni)
#pragma unroll
        for (int ks = 0; ks < 2; ++ks)
          acc[4 + mi][ni] = __builtin_amdgcn_mfma_f32_16x16x32_bf16(af[mi][ks], bf[ni][ks], acc[4 + mi][ni], 0, 0, 0);
    __builtin_amdgcn_s_setprio(0);
    __builtin_amdgcn_s_barrier();
    // ---- ph3: stage A rows64-127(u); MFMA q3; stage B half1(u); vmcnt; bar ----
    if (st) { SA(s, 0, 1, u); SA(s, 1, 1, u); }
    __builtin_amdgcn_s_barrier();
    __builtin_amdgcn_s_setprio(1);
#pragma unroll
    for (int mi = 0; mi < 4; ++mi)
#pragma unroll
      for (int ni = 0; ni < 2; ++ni)
#pragma unroll
        for (int ks = 0; ks < 2; ++ks)
          acc[4 + mi][2 + ni] = __builtin_amdgcn_mfma_f32_16x16x32_bf16(af[mi][ks], bf[2 + ni][ks], acc[4 + mi][2 + ni], 0, 0, 0);
    __builtin_amdgcn_s_setprio(0);
    if (st) { SB(s, 1, 0, u); SB(s, 1, 1, u); }
    if (t < 14) {
      asm volatile("s_waitcnt vmcnt(8)" ::: "memory");
    } else if (t == 14) {
      asm volatile("s_waitcnt vmcnt(0)" ::: "memory");
    }
    __builtin_amdgcn_s_barrier();
  }
#undef SA
#undef SB

  // ---- epilogue: scatter q/k/v + fused RoPE ----
  const int part = n0 >> 10;  // 0=q 1=k 2=v (256 | 1024, no straddle)
  if (part <= 1) {
    const float sc = (part == 0) ? qscale : 1.f;
    u16* dst = (part == 0) ? qw : kw;
#pragma unroll
    for (int mi = 0; mi < 8; ++mi) {
#pragma unroll
      for (int ni = 0; ni < 4; ++ni) {
        int col = n0 + wc * 64 + ni * 16 + a15;
        int rem = col & 1023, h = rem >> 6, d = rem & 63;
        int row = m0 + wr * 128 + mi * 16 + g * 4;
        int b = row >> 11, n = row & 2047;
        size_t bh = (size_t)b * 16 + h;
#pragma unroll
        for (int r = 0; r < 4; ++r) {
          float v = acc[mi][ni][r];
          float p = __shfl_xor(v, 1);
          float outv = v;
          if (d < 32) {
            int nr = n + r;
            float c = cs[nr * 32 + d], s2 = sn[nr * 32 + d];
            outv = v * c + ((d & 1) ? p * s2 : -p * s2);
          }
          dst[(bh * 2048 + n + r) * 64 + d] = f2bf(outv * sc);
        }
      }
    }
  } else {
#pragma unroll
    for (int mi = 0; mi < 8; ++mi) {
#pragma unroll
      for (int ni = 0; ni < 4; ++ni) {
        int col = n0 + wc * 64 + ni * 16 + a15;
        int rem = col & 1023, h = rem >> 6, d = rem & 63;
        int row = m0 + wr * 128 + mi * 16 + g * 4;
        int b = row >> 11, n = row & 2047;
        size_t bh = (size_t)b * 16 + h;
        ushort4 pk;
        pk.x = f2bf(acc[mi][ni][0]); pk.y = f2bf(acc[mi][ni][1]);
        pk.z = f2bf(acc[mi][ni][2]); pk.w = f2bf(acc[mi][ni][3]);
        *(ushort4*)&vw[(bh * 64 + d) * 2048 + n] = pk;  // v^T: (bh, d, n)
      }
    }
  }
}

// ---------------- out GEMM: 128x128 m97-structure (proven) ----------------
template <int EPI>
__global__ __launch_bounds__(256) void k_gemm(
    const u16* __restrict__ A, const u16* __restrict__ Bt,
    int M, int N, int K, float* __restrict__ of) {
  __shared__ __align__(16) u16 As[128 * 64];
  __shared__ __align__(16) u16 Bs[128 * 64];
  const int t = threadIdx.x;
  const int wv = t >> 6, lane = t & 63;
  const int a15 = lane & 15, g = lane >> 4;
  const int wr = wv >> 1, wc = wv & 1;
  const int m0 = blockIdx.x * 128, n0 = blockIdx.y * 128;
  const int gr = lane >> 3, gc = (lane & 7) * 8;

  f32x4 acc[4][4];
#pragma unroll
  for (int i = 0; i < 4; ++i)
#pragma unroll
    for (int j = 0; j < 4; ++j)
#pragma unroll
      for (int r = 0; r < 4; ++r) acc[i][j][r] = 0.f;

  for (int k0 = 0; k0 < K; k0 += 64) {
#pragma unroll
    for (int c4 = 0; c4 < 4; ++c4) {
      int c = wv * 4 + c4;
      g2l16(A + (size_t)(m0 + c * 8 + gr) * K + k0 + gc, &As[c * 512]);
      g2l16(Bt + (size_t)(n0 + c * 8 + gr) * K + k0 + gc, &Bs[c * 512]);
    }
    __syncthreads();
#pragma unroll
    for (int ks = 0; ks < 2; ++ks) {
      short8 af[4], bf[4];
#pragma unroll
      for (int mi = 0; mi < 4; ++mi)
        af[mi] = *(const short8*)&As[(wr * 64 + mi * 16 + a15) * 64 + ks * 32 + g * 8];
#pragma unroll
      for (int ni = 0; ni < 4; ++ni)
        bf[ni] = *(const short8*)&Bs[(wc * 64 + ni * 16 + a15) * 64 + ks * 32 + g * 8];
#pragma unroll
      for (int mi = 0; mi < 4; ++mi)
#pragma unroll
        for (int ni = 0; ni < 4; ++ni)
          acc[mi][ni] = __builtin_amdgcn_mfma_f32_16x16x32_bf16(af[mi], bf[ni], acc[mi][ni], 0, 0, 0);
    }
    __syncthreads();
  }

#pragma unroll
  for (int mi = 0; mi < 4; ++mi)
#pragma unroll
    for (int ni = 0; ni < 4; ++ni) {
      int col = n0 + wc * 64 + ni * 16 + a15;
      int row = m0 + wr * 64 + mi * 16 + g * 4;
#pragma unroll
      for (int r = 0; r < 4; ++r)
        of[(size_t)(row + r) * N + col] = acc[mi][ni][r];
    }
}

// ---------------- fused flash attention (frozen round-9 best: 100.5us) ----------------
__global__ __launch_bounds__(256, 3) void k_attn(
    const u16* __restrict__ q, const u16* __restrict__ kk, const u16* __restrict__ vT,
    u16* __restrict__ o) {
  __shared__ __align__(16) u16 Ks[2][4096];
  __shared__ __align__(16) u16 Vs[2][4096];
  __shared__ __align__(16) u16 Pl[4][1024];
  const int t = threadIdx.x;
  const int w = t >> 6, lane = t & 63;
  const int a15 = lane & 15, g = lane >> 4;
  const int id = blockIdx.x;
  const int bh = (id & 7) | ((id >> 7) << 3);   // XCD-local head
  const int qb = (id >> 3) & 15;
  const int q0 = qb * 128 + w * 32;
  const size_t hb = (size_t)bh * (2048 * 64);

  short8 qf[2][2];
#pragma unroll
  for (int f = 0; f < 2; ++f)
#pragma unroll
    for (int h = 0; h < 2; ++h)
      qf[f][h] = *(const short8*)&q[hb + (size_t)(q0 + f * 16 + a15) * 64 + h * 32 + g * 8];

  int ksrc[2], vsrc[2];
#pragma unroll
  for (int c = 0; c < 2; ++c) {
    int L = w * 2048 + c * 1024 + lane * 16;
    int row = L >> 7;
    int sb = L ^ ((row & 7) << 4);
    ksrc[c] = sb >> 1;
    vsrc[c] = row * 2048 + ((sb & 127) >> 1);
  }
  const u16* kg = kk + hb;
  const u16* vg = vT + (size_t)bh * (64 * 2048);

#define STAGE(b, j0) do {                                        \
    g2l16(kg + (size_t)(j0) * 64 + ksrc[0], &Ks[b][w * 1024]);   \
    g2l16(kg + (size_t)(j0) * 64 + ksrc[1], &Ks[b][w * 1024 + 512]); \
    g2l16(vg + (j0) + vsrc[0], &Vs[b][w * 1024]);                \
    g2l16(vg + (j0) + vsrc[1], &Vs[b][w * 1024 + 512]);          \
  } while (0)

  const f32x4 z4 = {0.f, 0.f, 0.f, 0.f};
  const short8 ones = {(short)0x3F80, (short)0x3F80, (short)0x3F80, (short)0x3F80,
                       (short)0x3F80, (short)0x3F80, (short)0x3F80, (short)0x3F80};
  f32x4 accO[2][4], ssum[2];
#pragma unroll
  for (int f = 0; f < 2; ++f) {
    ssum[f] = z4;
#pragma unroll
    for (int dc = 0; dc < 4; ++dc) accO[f][dc] = z4;
  }

  STAGE(0, 0);
  int cur = 0;
  for (int jt = 0; jt < 32; ++jt) {
    __syncthreads();
    if (jt < 31) STAGE(cur ^ 1, (jt + 1) * 64);

    f32x4 st[2][4];
    const char* Kb = (const char*)Ks[cur];
    __builtin_amdgcn_s_setprio(1);
#pragma unroll
    for (int jc = 0; jc < 4; ++jc) {
      int row = jc * 16 + a15;
      int sw = (row & 7) << 4;
      short8 ka0 = *(const short8*)(Kb + ((row * 128 + g * 16) ^ sw));
      short8 ka1 = *(const short8*)(Kb + ((row * 128 + 64 + g * 16) ^ sw));
      st[0][jc] = __builtin_amdgcn_mfma_f32_16x16x32_bf16(ka0, qf[0][0], z4, 0, 0, 0);
      st[0][jc] = __builtin_amdgcn_mfma_f32_16x16x32_bf16(ka1, qf[0][1], st[0][jc], 0, 0, 0);
      st[1][jc] = __builtin_amdgcn_mfma_f32_16x16x32_bf16(ka0, qf[1][0], z4, 0, 0, 0);
      st[1][jc] = __builtin_amdgcn_mfma_f32_16x16x32_bf16(ka1, qf[1][1], st[1][jc], 0, 0, 0);
    }
    __builtin_amdgcn_s_setprio(0);
    short8 vf[2][4];
    const char* Vb = (const char*)Vs[cur];
#pragma unroll
    for (int kt = 0; kt < 2; ++kt)
#pragma unroll
      for (int dc = 0; dc < 4; ++dc) {
        int row = dc * 16 + a15;
        vf[kt][dc] = *(const short8*)(Vb + ((row * 128 + kt * 64 + g * 16) ^ ((row & 7) << 4)));
      }
#pragma unroll
    for (int f = 0; f < 2; ++f) {
#pragma unroll
      for (int jc = 0; jc < 4; ++jc) {
        float e0 = __builtin_amdgcn_exp2f(st[f][jc][0]);
        float e1 = __builtin_amdgcn_exp2f(st[f][jc][1]);
        float e2 = __builtin_amdgcn_exp2f(st[f][jc][2]);
        float e3 = __builtin_amdgcn_exp2f(st[f][jc][3]);
        uint2 pw;
        pw.x = pk_trunc(e0, e1);
        pw.y = pk_trunc(e2, e3);
        int byte = (a15 * 128 + (jc * 16 + g * 4) * 2) ^ ((a15 & 7) << 4);
        *(uint2*)((char*)Pl[w] + byte) = pw;
      }
      __builtin_amdgcn_s_setprio(1);
#pragma unroll
      for (int kt = 0; kt < 2; ++kt) {
        int byteA = (a15 * 128 + kt * 64 + g * 16) ^ ((a15 & 7) << 4);
        short8 pa = *(const short8*)((const char*)Pl[w] + byteA);
        ssum[f] = __builtin_amdgcn_mfma_f32_16x16x32_bf16(pa, ones, ssum[f], 0, 0, 0);
#pragma unroll
        for (int dc = 0; dc < 4; ++dc)
          accO[f][dc] = __builtin_amdgcn_mfma_f32_16x16x32_bf16(pa, vf[kt][dc], accO[f][dc], 0, 0, 0);
      }
      __builtin_amdgcn_s_setprio(0);
    }
    cur ^= 1;
  }
#undef STAGE

  const int b = bh >> 4, h = bh & 15;
#pragma unroll
  for (int f = 0; f < 2; ++f) {
    float rs[4];
#pragma unroll
    for (int r = 0; r < 4; ++r) rs[r] = 1.f / ssum[f][r];
#pragma unroll
    for (int dc = 0; dc < 4; ++dc)
#pragma unroll
      for (int r = 0; r < 4; ++r) {
        int n = q0 + f * 16 + g * 4 + r;
        o[((size_t)b * 2048 + n) * 1024 + h * 64 + dc * 16 + a15] = f2bf(accO[f][dc][r] * rs[r]);
      }
  }
}

extern "C" void kernel_launch(void* const* d_in, const int* in_sizes, int n_in,
                              void* d_out, int out_size, void* d_ws, size_t ws_size,
                              hipStream_t stream) {
  const float* x = (const float*)d_in[0];
  const float* sn = (const float*)d_in[1];
  const float* cs = (const float*)d_in[2];
  const float* Wqkv = (const float*)d_in[3];
  const float* Wout = (const float*)d_in[4];
  float* out = (float*)d_out;

  u16* ws = (u16*)d_ws;
  u16* xb = ws;                              // 8192*1024
  u16* wqkvT = xb + 8192ull * 1024;          // 3072*1024
  u16* woutT = wqkvT + 3072ull * 1024;       // 1024*1024
  u16* qw = woutT + 1024ull * 1024;          // 64*2048*64
  u16* kw = qw + 64ull * 2048 * 64;
  u16* vw = kw + 64ull * 2048 * 64;
  u16* attn = xb;  // alias: x consumed by QKV GEMM before attention writes

  const float qscale = 0.125f * 1.4426950408889634f;  // DH^-0.5 * log2(e)

  k_prep<<<12288, 256, 0, stream>>>(x, xb, Wqkv, wqkvT, Wout, woutT);
  k_gemm0<<<384, 512, 0, stream>>>(xb, wqkvT, qw, kw, vw, sn, cs, qscale);
  k_attn<<<1024, 256, 0, stream>>>(qw, kw, vw, attn);
  k_gemm<1><<<dim3(64, 8), 256, 0, stream>>>(attn, woutT, 8192, 1024, 1024, out);
}